// Round 19
// baseline (333.819 us; speedup 1.0000x reference)
//
#include <hip/hip_runtime.h>
#include <stdint.h>

#define NB 16
#define NM 64
#define NS 256
#define NE 256
#define NH 256

// ---------------- threefry2x32 (jax-exact) ----------------
__device__ __forceinline__ uint32_t rotl32(uint32_t v, int d) { return (v << d) | (v >> (32 - d)); }

__device__ __forceinline__ void threefry(uint32_t k0, uint32_t k1,
                                         uint32_t x0, uint32_t x1,
                                         uint32_t& o0, uint32_t& o1) {
  uint32_t ks2 = k0 ^ k1 ^ 0x1BD11BDAu;
#define TFR(r) { x0 += x1; x1 = rotl32(x1, r); x1 ^= x0; }
  x0 += k0; x1 += k1;
  TFR(13) TFR(15) TFR(26) TFR(6)
  x0 += k1;  x1 += ks2 + 1u;
  TFR(17) TFR(29) TFR(16) TFR(24)
  x0 += ks2; x1 += k0 + 2u;
  TFR(13) TFR(15) TFR(26) TFR(6)
  x0 += k0;  x1 += k1 + 3u;
  TFR(17) TFR(29) TFR(16) TFR(24)
  x0 += k1;  x1 += ks2 + 4u;
  TFR(13) TFR(15) TFR(26) TFR(6)
  x0 += ks2; x1 += k0 + 5u;
#undef TFR
  o0 = x0; o1 = x1;
}

__device__ __forceinline__ float gumbel_from_bits(uint32_t bits) {
  float u = __uint_as_float((bits >> 9) | 0x3f800000u) - 1.0f;
  u = fmaxf(u, 1.17549435e-38f);
  return -logf(-logf(u));
}

// ---------------- fused pre-kernel bodies (IDENTICAL to R18) ----------------
__device__ void gumbel_body(int blk, float* __restrict__ g) {
  const int b = blk >> 6;
  const int i = blk & 63;
  const int s = threadIdx.x;        // 0..255
  uint32_t kb0, kb1, f0, f1, r0, r1;
  threefry(0u, 42u, 0u, (uint32_t)b, kb0, kb1);
  threefry(kb0, kb1, 0u, (uint32_t)i, f0, f1);
  threefry(f0, f1, 0u, (uint32_t)s, r0, r1);
  g[(blk << 8) + s] = gumbel_from_bits(r0 ^ r1);
}

__device__ void prep_body(int b,
                          const float* __restrict__ emb,
                          const float* __restrict__ init_w,
                          const float* __restrict__ Whc,
                          const float* __restrict__ bhc,
                          const float* __restrict__ Wv,
                          const float* __restrict__ bv,
                          const float* __restrict__ Wq,
                          float* __restrict__ qbase,
                          float* __restrict__ q0W,
                          float* __restrict__ smem) {
  const int t = threadIdx.x;
  float* mean_s = smem;            // [NE]
  float* hbpb   = smem + NE;       // [NE]
  float* iwv    = smem + 2 * NE;   // [NE]
  const float* eb = emb + (size_t)b * NS * NE;
  float acc = 0.f;
  for (int s = 0; s < NS; ++s) acc += eb[s * NE + t];
  mean_s[t] = acc * (1.0f / NS);
  __syncthreads();
  float h = bhc[t];
  for (int j = 0; j < NE; ++j) h = fmaf(mean_s[j], Whc[j * NE + t], h);
  hbpb[t] = h + bv[t];
  float a2 = 0.f;
  for (int j = 0; j < 2 * NE; ++j) a2 = fmaf(init_w[j], Wv[j * NE + t], a2);
  iwv[t] = a2;
  __syncthreads();
  float qb = 0.f, q0 = 0.f;
  for (int e = 0; e < NE; ++e) {
    float w = Wq[e * NH + t];
    qb = fmaf(hbpb[e], w, qb);
    q0 = fmaf(hbpb[e] + iwv[e], w, q0);
  }
  qbase[b * NH + t] = qb;
  q0W[b * NH + t] = q0;
}

__device__ void mm_body(int blk,
                        const float* __restrict__ A,
                        const float* __restrict__ W,
                        float* __restrict__ C) {
  const int t = threadIdx.x;
  const int hq = (t & 63) * 4;
  const int r0 = (t >> 6) * 4;
  const int rowbase = blk * 16;
  float acc[4][4] = {};
  #pragma unroll 2
  for (int e = 0; e < NE; ++e) {
    float4 w = *(const float4*)(W + e * NH + hq);
    #pragma unroll
    for (int r = 0; r < 4; ++r) {
      float a = A[(size_t)(rowbase + r0 + r) * NE + e];
      acc[r][0] = fmaf(a, w.x, acc[r][0]);
      acc[r][1] = fmaf(a, w.y, acc[r][1]);
      acc[r][2] = fmaf(a, w.z, acc[r][2]);
      acc[r][3] = fmaf(a, w.w, acc[r][3]);
    }
  }
  #pragma unroll
  for (int r = 0; r < 4; ++r)
    *(float4*)(C + (size_t)(rowbase + r0 + r) * NH + hq) =
        make_float4(acc[r][0], acc[r][1], acc[r][2], acc[r][3]);
}

#define TPAD 260
__device__ void mm2_fused_body(int blk,
                               const float* __restrict__ emb,
                               const float* __restrict__ Wvb,
                               const float* __restrict__ Wq,
                               float* __restrict__ EQB,
                               float* __restrict__ sm) {
  const int t = threadIdx.x;
  const int hq = (t & 63) * 4;
  const int r0 = (t >> 6) * 4;
  const int rowbase = blk * 16;
  {
    float acc1[4][4] = {};
    #pragma unroll 2
    for (int e = 0; e < NE; ++e) {
      float4 w = *(const float4*)(Wvb + e * NE + hq);
      #pragma unroll
      for (int r = 0; r < 4; ++r) {
        float a = emb[(size_t)(rowbase + r0 + r) * NE + e];
        acc1[r][0] = fmaf(a, w.x, acc1[r][0]);
        acc1[r][1] = fmaf(a, w.y, acc1[r][1]);
        acc1[r][2] = fmaf(a, w.z, acc1[r][2]);
        acc1[r][3] = fmaf(a, w.w, acc1[r][3]);
      }
    }
    #pragma unroll
    for (int r = 0; r < 4; ++r)
      *(float4*)&sm[(r0 + r) * TPAD + hq] =
          make_float4(acc1[r][0], acc1[r][1], acc1[r][2], acc1[r][3]);
  }
  __syncthreads();
  float acc[4][4] = {};
  for (int e4 = 0; e4 < NE; e4 += 4) {
    float4 a4[4];
    #pragma unroll
    for (int r = 0; r < 4; ++r) a4[r] = *(const float4*)&sm[(r0 + r) * TPAD + e4];
    #pragma unroll
    for (int ee = 0; ee < 4; ++ee) {
      float4 w = *(const float4*)(Wq + (e4 + ee) * NH + hq);
      #pragma unroll
      for (int r = 0; r < 4; ++r) {
        float a = (ee == 0) ? a4[r].x : (ee == 1) ? a4[r].y : (ee == 2) ? a4[r].z : a4[r].w;
        acc[r][0] = fmaf(a, w.x, acc[r][0]);
        acc[r][1] = fmaf(a, w.y, acc[r][1]);
        acc[r][2] = fmaf(a, w.z, acc[r][2]);
        acc[r][3] = fmaf(a, w.w, acc[r][3]);
      }
    }
  }
  #pragma unroll
  for (int r = 0; r < 4; ++r)
    *(float4*)(EQB + (size_t)(rowbase + r0 + r) * NH + hq) =
        make_float4(__expf(2.f * acc[r][0]), __expf(2.f * acc[r][1]),
                    __expf(2.f * acc[r][2]), __expf(2.f * acc[r][3]));
}

__global__ __launch_bounds__(256) void fused_pre_kernel(
    float* __restrict__ g,
    const float* __restrict__ emb,
    const float* __restrict__ init_w,
    const float* __restrict__ Whc,
    const float* __restrict__ bhc,
    const float* __restrict__ Wv,
    const float* __restrict__ bv,
    const float* __restrict__ Wq,
    const float* __restrict__ Wk,
    float* __restrict__ qbase,
    float* __restrict__ q0W,
    float* __restrict__ kp,
    float* __restrict__ EQB) {
  __shared__ float smem[16 * TPAD];
  const int blk = blockIdx.x;
  if (blk < 256) {
    mm2_fused_body(blk, emb, Wv + NE * NE, Wq, EQB, smem);
  } else if (blk < 512) {
    mm_body(blk - 256, emb, Wk, kp);
  } else if (blk < 512 + NB * NM) {
    gumbel_body(blk - 512, g);
  } else {
    prep_body(blk - 512 - NB * NM, emb, init_w, Whc, bhc, Wv, bv, Wq, qbase, q0W, smem);
  }
}

#define PIDX(h) (((h) >> 5) * 36 + ((h) & 31))

// ---------------- sequential decode: 1 block per batch item ----------------
// R19: ONE barrier per step. Each wave stages the full EQB[idx] row into its OWN
// qW_w slice (wave-local LDS write->read needs only lgkmcnt, no barrier); part4 is
// double-buffered by step parity so only the cross-wave argmax publish needs sync.
// e2qb lives in LDS (eqb_s) — zero persistent VGPR cost; ek stays read-only 64 regs.
__global__ __launch_bounds__(1024, 4) void decode_kernel(
    const float* __restrict__ emb,
    const float* __restrict__ node,
    const float* __restrict__ costs,
    const float* __restrict__ Wv,
    const float* __restrict__ Wq,
    const float* __restrict__ vptr,
    const float* __restrict__ g_g,
    const float* __restrict__ kp_g,
    const float* __restrict__ EQB_g,       // = exp(2*QB)
    const float* __restrict__ qbase_g,
    const float* __restrict__ q0W_g,
    float* __restrict__ out) {
  const int b = blockIdx.x;
  const int tid = threadIdx.x;
  const int hc = tid & 7;          // 32-float h-chunk
  const int pr = tid >> 3;         // s-pair 0..127
  const int s0 = pr * 2, s1 = s0 + 1;
  const int wid = tid >> 6;        // wave 0..15
  const int lane = tid & 63;

  __shared__ float qW_w[16][8 * 36];   // PER-WAVE e^{2q} slices
  __shared__ float vpp[8 * 36];        // -2*vptr
  __shared__ float eqb_s[NS];          // e2qb per h (LDS, not regs)
  __shared__ float4 part4[2][16];      // double-buffered per-wave argmax partials
  __shared__ float2 mle[NM][17];       // per-step per-wave {max lg, sum exp}
  __shared__ float blg_hist[NM];
  __shared__ int   idx_hist[NM];
  __shared__ float er[NE];
  __shared__ float Ts[NE];

  // ek = exp(2*kp) for 2 s x 32 h — READ-ONLY persistent block (64 VGPRs)
  float4 ek0[8], ek1[8];
  {
    const float4* p0 = (const float4*)(kp_g + ((size_t)b * NS + s0) * NH + hc * 32);
    const float4* p1 = (const float4*)(kp_g + ((size_t)b * NS + s1) * NH + hc * 32);
    #pragma unroll
    for (int j = 0; j < 8; ++j) {
      float4 a = p0[j], c = p1[j];
      ek0[j] = make_float4(__expf(2.f * a.x), __expf(2.f * a.y), __expf(2.f * a.z), __expf(2.f * a.w));
      ek1[j] = make_float4(__expf(2.f * c.x), __expf(2.f * c.y), __expf(2.f * c.z), __expf(2.f * c.w));
    }
  }
  float Vsum = 0.f;
  {
    const float4* vv = (const float4*)(vptr + hc * 32);
    #pragma unroll
    for (int j = 0; j < 8; ++j) { float4 v = vv[j]; Vsum += (v.x + v.y) + (v.z + v.w); }
  }
  if (tid < NH) {
    vpp[PIDX(tid)] = -2.0f * vptr[tid];
    eqb_s[tid] = __expf(2.0f * qbase_g[b * NH + tid]);
  }
  // every wave inits ITS OWN qW slice with exp(2*q0W): lane l covers h=4l..4l+3
  {
    float4 q0 = *(const float4*)(q0W_g + b * NH + 4 * lane);
    *(float4*)(&qW_w[wid][PIDX(4 * lane)]) =
        make_float4(__expf(2.f * q0.x), __expf(2.f * q0.y), __expf(2.f * q0.z), __expf(2.f * q0.w));
  }

  int m = 0;
  const float* gb = g_g + (size_t)b * NM * NS;

  __syncthreads();

  for (int i = 0; i < NM; ++i) {
    // ---- phase A+B fused: per-pair logits + full per-wave reduce (own qW slice) ----
    float lg0, lg1, val0, val1;
    if (!m) {
      float2 g01 = *(const float2*)(gb + i * NS + s0);
      const float4* q4 = (const float4*)(&qW_w[wid][hc * 36]);
      const float4* v4 = (const float4*)(vpp + hc * 36);
      float a0 = 0.f, a1 = 0.f;
      #pragma unroll
      for (int jj = 0; jj < 4; ++jj) {
        float4 qa = q4[2 * jj], qb = q4[2 * jj + 1];
        float4 va = v4[2 * jj], vb = v4[2 * jj + 1];
        {
          float4 ka = ek0[2 * jj], kb = ek0[2 * jj + 1];
          float z1 = fmaf(qa.x, ka.x, 1.f), z2 = fmaf(qa.y, ka.y, 1.f);
          float z3 = fmaf(qa.z, ka.z, 1.f), z4 = fmaf(qa.w, ka.w, 1.f);
          float z5 = fmaf(qb.x, kb.x, 1.f), z6 = fmaf(qb.y, kb.y, 1.f);
          float z7 = fmaf(qb.z, kb.z, 1.f), z8 = fmaf(qb.w, kb.w, 1.f);
          float p12 = z1 * z2, p34 = z3 * z4, p56 = z5 * z6, p78 = z7 * z8;
          float p1234 = p12 * p34, p5678 = p56 * p78;
          float r = __builtin_amdgcn_rcpf(p1234 * p5678);
          float t12 = fmaf(va.y, z1, va.x * z2);
          float t34 = fmaf(va.w, z3, va.z * z4);
          float t56 = fmaf(vb.y, z5, vb.x * z6);
          float t78 = fmaf(vb.w, z7, vb.z * z8);
          float T14 = fmaf(t34, p12, t12 * p34);
          float T58 = fmaf(t78, p56, t56 * p78);
          a0 = fmaf(T14 * p5678, r, a0);
          a0 = fmaf(T58 * p1234, r, a0);
        }
        {
          float4 ka = ek1[2 * jj], kb = ek1[2 * jj + 1];
          float z1 = fmaf(qa.x, ka.x, 1.f), z2 = fmaf(qa.y, ka.y, 1.f);
          float z3 = fmaf(qa.z, ka.z, 1.f), z4 = fmaf(qa.w, ka.w, 1.f);
          float z5 = fmaf(qb.x, kb.x, 1.f), z6 = fmaf(qb.y, kb.y, 1.f);
          float z7 = fmaf(qb.z, kb.z, 1.f), z8 = fmaf(qb.w, kb.w, 1.f);
          float p12 = z1 * z2, p34 = z3 * z4, p56 = z5 * z6, p78 = z7 * z8;
          float p1234 = p12 * p34, p5678 = p56 * p78;
          float r = __builtin_amdgcn_rcpf(p1234 * p5678);
          float t12 = fmaf(va.y, z1, va.x * z2);
          float t34 = fmaf(va.w, z3, va.z * z4);
          float t56 = fmaf(vb.y, z5, vb.x * z6);
          float t78 = fmaf(vb.w, z7, vb.z * z8);
          float T14 = fmaf(t34, p12, t12 * p34);
          float T58 = fmaf(t78, p56, t56 * p78);
          a1 = fmaf(T14 * p5678, r, a1);
          a1 = fmaf(T58 * p1234, r, a1);
        }
      }
      float u0 = Vsum + a0;
      float u1 = Vsum + a1;
      u0 += __shfl_xor(u0, 1); u0 += __shfl_xor(u0, 2); u0 += __shfl_xor(u0, 4);
      u1 += __shfl_xor(u1, 1); u1 += __shfl_xor(u1, 2); u1 += __shfl_xor(u1, 4);
      float ex0 = __expf(2.f * u0);
      float ex1 = __expf(2.f * u1);
      lg0 = fmaf(-20.f, __builtin_amdgcn_rcpf(ex0 + 1.f), 10.f);
      lg1 = fmaf(-20.f, __builtin_amdgcn_rcpf(ex1 + 1.f), 10.f);
      val0 = lg0 + g01.x;
      val1 = lg1 + g01.y;
    } else {
      lg0 = -1e9f; lg1 = -1e9f; val0 = -1e9f; val1 = -1e9f;
    }
    // wave-wide max(lg)
    float ml = fmaxf(lg0, lg1);
    #pragma unroll
    for (int off = 1; off < 64; off <<= 1) ml = fmaxf(ml, __shfl_xor(ml, off));
    // wave-wide sum exp(lg-ml): each pair replicated 8x -> scale by 1/8
    float e = (__expf(lg0 - ml) + __expf(lg1 - ml)) * 0.125f;
    #pragma unroll
    for (int off = 1; off < 64; off <<= 1) e += __shfl_xor(e, off);
    // wave-wide argmax carrying (val, idx, lg); first-index tiebreak
    bool t1 = val1 > val0;
    float v = t1 ? val1 : val0;
    int vi = t1 ? s1 : s0;
    float lgw = t1 ? lg1 : lg0;
    #pragma unroll
    for (int off = 1; off < 64; off <<= 1) {
      float ov = __shfl_xor(v, off);
      int   oi = __shfl_xor(vi, off);
      float ol = __shfl_xor(lgw, off);
      bool take = (ov > v) || (ov == v && oi < vi);
      v   = take ? ov : v;
      vi  = take ? oi : vi;
      lgw = take ? ol : lgw;
    }
    if (lane == 0) {
      part4[i & 1][wid] = make_float4(v, __int_as_float(vi), lgw, 0.f);
      mle[i][wid] = make_float2(ml, e);
    }
    __syncthreads();                                    // THE barrier (part4 publish)

    // ---- combine on every lane ----
    float4 p = part4[i & 1][lane & 15];
    float cv = p.x; int ci = __float_as_int(p.y); float cl = p.z;
    #pragma unroll
    for (int off = 1; off < 16; off <<= 1) {
      float ov = __shfl_xor(cv, off);
      int   oi = __shfl_xor(ci, off);
      float ol = __shfl_xor(cl, off);
      bool take = (ov > cv) || (ov == cv && oi < ci);
      cv = take ? ov : cv;
      ci = take ? oi : ci;
      cl = take ? ol : cl;
    }
    const int idx = ci;
    if (tid == 0) { idx_hist[i] = idx; blg_hist[i] = cl; }

    // mask whole 4-node cell of idx
    if (!m && (pr >> 1) == (idx >> 2)) m = 1;

    // one-time after step 0: fold exp(2*Qinit) into eqb_s
    if (i == 0) {
      if (tid < NE) er[tid] = emb[((size_t)b * NS + idx) * NE + tid];
      __syncthreads();
      if (tid < NE) {
        float tv = 0.f;
        #pragma unroll 4
        for (int j = 0; j < NE; ++j) tv = fmaf(er[j], Wv[j * NE + tid], tv);
        Ts[tid] = tv;
      }
      __syncthreads();
      if (tid < NE) {
        float qi = 0.f;
        #pragma unroll 4
        for (int e2 = 0; e2 < NE; ++e2) qi = fmaf(Ts[e2], Wq[e2 * NH + tid], qi);
        eqb_s[tid] *= __expf(2.0f * qi);
      }
      __syncthreads();                                  // eqb_s visible (one-time)
    }

    // ---- per-wave staging of next step's e^{2q} into OWN slice (no barrier) ----
    if (i + 1 < NM && !__all(m)) {
      float4 eq = *(const float4*)(EQB_g + ((size_t)b * NS + idx) * NH + 4 * lane);
      float e0 = eqb_s[4 * lane + 0];
      float e1 = eqb_s[4 * lane + 1];
      float e2v = eqb_s[4 * lane + 2];
      float e3 = eqb_s[4 * lane + 3];
      *(float4*)(&qW_w[wid][PIDX(4 * lane)]) =
          make_float4(eq.x * e0, eq.y * e1, eq.z * e2v, eq.w * e3);
      asm volatile("s_waitcnt lgkmcnt(0)" ::: "memory");  // own-wave write->read ordering
    }
  }

  __syncthreads();                                      // hist arrays visible to epilogue

  // ---- post-loop: wave 0 = logp (one step per lane), wave 1 = reward ----
  if (wid == 0) {
    float mlg = -3.0e38f;
    #pragma unroll 4
    for (int w = 0; w < 16; ++w) mlg = fmaxf(mlg, mle[lane][w].x);
    float sum = 0.f;
    #pragma unroll 4
    for (int w = 0; w < 16; ++w) {
      float2 me = mle[lane][w];
      sum += me.y * __expf(me.x - mlg);
    }
    float term = blg_hist[lane] - (mlg + logf(sum));
    #pragma unroll
    for (int off = 1; off < 64; off <<= 1) term += __shfl_xor(term, off);
    if (lane == 0) out[b] = term;
    out[2 * NB + b * NM + lane] = (float)idx_hist[lane];
  } else if (wid == 1) {
    float term = 0.f;
    if (lane > 0) {
      int id = idx_hist[lane];
      int pv = idx_hist[lane - 1];
      float dx = node[((size_t)b * NS + id) * 4 + 0] - node[((size_t)b * NS + pv) * 4 + 2];
      float dy = node[((size_t)b * NS + id) * 4 + 1] - node[((size_t)b * NS + pv) * 4 + 3];
      term = sqrtf(dx * dx + dy * dy) + costs[(size_t)b * NS + pv] + costs[(size_t)b * NS + id];
    }
    #pragma unroll
    for (int off = 1; off < 64; off <<= 1) term += __shfl_xor(term, off);
    if (lane == 0) out[NB + b] = term;
  }
}

extern "C" void kernel_launch(void* const* d_in, const int* in_sizes, int n_in,
                              void* d_out, int out_size, void* d_ws, size_t ws_size,
                              hipStream_t stream) {
  const float* emb    = (const float*)d_in[0];
  const float* node   = (const float*)d_in[1];
  const float* costs  = (const float*)d_in[4];
  const float* init_w = (const float*)d_in[5];
  const float* Whc    = (const float*)d_in[6];
  const float* bhc    = (const float*)d_in[7];
  const float* Wv     = (const float*)d_in[8];
  const float* bv     = (const float*)d_in[9];
  const float* Wq     = (const float*)d_in[10];
  const float* Wk     = (const float*)d_in[11];
  const float* vptr   = (const float*)d_in[12];
  float* out = (float*)d_out;

  float* ws    = (float*)d_ws;
  float* g     = ws;
  float* kp    = g + NB * NM * NS;
  float* QB    = kp + (size_t)NB * NS * NH;
  float* spare = QB + (size_t)NB * NS * NH;
  float* qbase = spare + (size_t)NB * NS * NE;
  float* q0W   = qbase + NB * NH;

  fused_pre_kernel<<<512 + NB * NM + NB, 256, 0, stream>>>(
      g, emb, init_w, Whc, bhc, Wv, bv, Wq, Wk, qbase, q0W, kp, QB);
  decode_kernel<<<NB, 1024, 0, stream>>>(emb, node, costs, Wv, Wq, vptr,
                                         g, kp, QB, qbase, q0W, out);
}

// Round 20
// 330.974 us; speedup vs baseline: 1.0086x; 1.0086x over previous
//
#include <hip/hip_runtime.h>
#include <stdint.h>

#define NB 16
#define NM 64
#define NS 256
#define NE 256
#define NH 256

// ---------------- threefry2x32 (jax-exact) ----------------
__device__ __forceinline__ uint32_t rotl32(uint32_t v, int d) { return (v << d) | (v >> (32 - d)); }

__device__ __forceinline__ void threefry(uint32_t k0, uint32_t k1,
                                         uint32_t x0, uint32_t x1,
                                         uint32_t& o0, uint32_t& o1) {
  uint32_t ks2 = k0 ^ k1 ^ 0x1BD11BDAu;
#define TFR(r) { x0 += x1; x1 = rotl32(x1, r); x1 ^= x0; }
  x0 += k0; x1 += k1;
  TFR(13) TFR(15) TFR(26) TFR(6)
  x0 += k1;  x1 += ks2 + 1u;
  TFR(17) TFR(29) TFR(16) TFR(24)
  x0 += ks2; x1 += k0 + 2u;
  TFR(13) TFR(15) TFR(26) TFR(6)
  x0 += k0;  x1 += k1 + 3u;
  TFR(17) TFR(29) TFR(16) TFR(24)
  x0 += k1;  x1 += ks2 + 4u;
  TFR(13) TFR(15) TFR(26) TFR(6)
  x0 += ks2; x1 += k0 + 5u;
#undef TFR
  o0 = x0; o1 = x1;
}

__device__ __forceinline__ float gumbel_from_bits(uint32_t bits) {
  float u = __uint_as_float((bits >> 9) | 0x3f800000u) - 1.0f;
  u = fmaxf(u, 1.17549435e-38f);
  return -logf(-logf(u));
}

// ---------------- fused pre-kernel bodies ----------------
__device__ void gumbel_body(int blk, float* __restrict__ g) {
  const int b = blk >> 6;
  const int i = blk & 63;
  const int s = threadIdx.x;        // 0..255
  uint32_t kb0, kb1, f0, f1, r0, r1;
  threefry(0u, 42u, 0u, (uint32_t)b, kb0, kb1);
  threefry(kb0, kb1, 0u, (uint32_t)i, f0, f1);
  threefry(f0, f1, 0u, (uint32_t)s, r0, r1);
  g[(blk << 8) + s] = gumbel_from_bits(r0 ^ r1);
}

__device__ void prep_body(int b,
                          const float* __restrict__ emb,
                          const float* __restrict__ init_w,
                          const float* __restrict__ Whc,
                          const float* __restrict__ bhc,
                          const float* __restrict__ Wv,
                          const float* __restrict__ bv,
                          const float* __restrict__ Wq,
                          float* __restrict__ qbase,
                          float* __restrict__ q0W,
                          float* __restrict__ smem) {
  const int t = threadIdx.x;
  float* mean_s = smem;            // [NE]
  float* hbpb   = smem + NE;       // [NE]
  float* iwv    = smem + 2 * NE;   // [NE]
  const float* eb = emb + (size_t)b * NS * NE;
  float acc = 0.f;
  for (int s = 0; s < NS; ++s) acc += eb[s * NE + t];
  mean_s[t] = acc * (1.0f / NS);
  __syncthreads();
  float h = bhc[t];
  for (int j = 0; j < NE; ++j) h = fmaf(mean_s[j], Whc[j * NE + t], h);
  hbpb[t] = h + bv[t];
  float a2 = 0.f;
  for (int j = 0; j < 2 * NE; ++j) a2 = fmaf(init_w[j], Wv[j * NE + t], a2);
  iwv[t] = a2;
  __syncthreads();
  float qb = 0.f, q0 = 0.f;
  for (int e = 0; e < NE; ++e) {
    float w = Wq[e * NH + t];
    qb = fmaf(hbpb[e], w, qb);
    q0 = fmaf(hbpb[e] + iwv[e], w, q0);
  }
  qbase[b * NH + t] = qb;
  q0W[b * NH + t] = q0;
}

// plain GEMM: C[row][h] = sum_e A[row][e]*W[e][h], 16 rows per body-call
__device__ void mm_body(int blk,
                        const float* __restrict__ A,
                        const float* __restrict__ W,
                        float* __restrict__ C) {
  const int t = threadIdx.x;
  const int hq = (t & 63) * 4;
  const int r0 = (t >> 6) * 4;
  const int rowbase = blk * 16;
  float acc[4][4] = {};
  #pragma unroll 2
  for (int e = 0; e < NE; ++e) {
    float4 w = *(const float4*)(W + e * NH + hq);
    #pragma unroll
    for (int r = 0; r < 4; ++r) {
      float a = A[(size_t)(rowbase + r0 + r) * NE + e];   // wave-uniform -> scalar path
      acc[r][0] = fmaf(a, w.x, acc[r][0]);
      acc[r][1] = fmaf(a, w.y, acc[r][1]);
      acc[r][2] = fmaf(a, w.z, acc[r][2]);
      acc[r][3] = fmaf(a, w.w, acc[r][3]);
    }
  }
  #pragma unroll
  for (int r = 0; r < 4; ++r)
    *(float4*)(C + (size_t)(rowbase + r0 + r) * NH + hq) =
        make_float4(acc[r][0], acc[r][1], acc[r][2], acc[r][3]);
}

// chained GEMM: EQB rows = exp(2*((emb@Wv_bot)@Wq)) with the 16x256 intermediate in LDS.
// fmaf order identical to the two-pass version -> bit-identical EQB.
#define TPAD 260   // 16-row tile pad (multiple of 4 -> b128-aligned chunks)
__device__ void mm2_fused_body(int blk,
                               const float* __restrict__ emb,
                               const float* __restrict__ Wvb,
                               const float* __restrict__ Wq,
                               float* __restrict__ EQB,
                               float* __restrict__ sm) {
  const int t = threadIdx.x;
  const int hq = (t & 63) * 4;
  const int r0 = (t >> 6) * 4;
  const int rowbase = blk * 16;
  // ---- GEMM 1: tmp[r][hq..] = sum_e emb[row][e] * Wvb[e][hq..]  -> LDS ----
  {
    float acc1[4][4] = {};
    #pragma unroll 2
    for (int e = 0; e < NE; ++e) {
      float4 w = *(const float4*)(Wvb + e * NE + hq);
      #pragma unroll
      for (int r = 0; r < 4; ++r) {
        float a = emb[(size_t)(rowbase + r0 + r) * NE + e];
        acc1[r][0] = fmaf(a, w.x, acc1[r][0]);
        acc1[r][1] = fmaf(a, w.y, acc1[r][1]);
        acc1[r][2] = fmaf(a, w.z, acc1[r][2]);
        acc1[r][3] = fmaf(a, w.w, acc1[r][3]);
      }
    }
    #pragma unroll
    for (int r = 0; r < 4; ++r)
      *(float4*)&sm[(r0 + r) * TPAD + hq] =
          make_float4(acc1[r][0], acc1[r][1], acc1[r][2], acc1[r][3]);
  }
  __syncthreads();
  // ---- GEMM 2 + exp epilogue ----
  float acc[4][4] = {};
  for (int e4 = 0; e4 < NE; e4 += 4) {
    float4 a4[4];
    #pragma unroll
    for (int r = 0; r < 4; ++r) a4[r] = *(const float4*)&sm[(r0 + r) * TPAD + e4];  // broadcast
    #pragma unroll
    for (int ee = 0; ee < 4; ++ee) {
      float4 w = *(const float4*)(Wq + (e4 + ee) * NH + hq);
      #pragma unroll
      for (int r = 0; r < 4; ++r) {
        float a = (ee == 0) ? a4[r].x : (ee == 1) ? a4[r].y : (ee == 2) ? a4[r].z : a4[r].w;
        acc[r][0] = fmaf(a, w.x, acc[r][0]);
        acc[r][1] = fmaf(a, w.y, acc[r][1]);
        acc[r][2] = fmaf(a, w.z, acc[r][2]);
        acc[r][3] = fmaf(a, w.w, acc[r][3]);
      }
    }
  }
  #pragma unroll
  for (int r = 0; r < 4; ++r)
    *(float4*)(EQB + (size_t)(rowbase + r0 + r) * NH + hq) =
        make_float4(__expf(2.f * acc[r][0]), __expf(2.f * acc[r][1]),
                    __expf(2.f * acc[r][2]), __expf(2.f * acc[r][3]));
}

// ONE pre-kernel: [EQB-chained | mm1(kp) | gumbel | prep] — all independent; heavy first
__global__ __launch_bounds__(256) void fused_pre_kernel(
    float* __restrict__ g,
    const float* __restrict__ emb,
    const float* __restrict__ init_w,
    const float* __restrict__ Whc,
    const float* __restrict__ bhc,
    const float* __restrict__ Wv,
    const float* __restrict__ bv,
    const float* __restrict__ Wq,
    const float* __restrict__ Wk,
    float* __restrict__ qbase,
    float* __restrict__ q0W,
    float* __restrict__ kp,
    float* __restrict__ EQB) {
  __shared__ float smem[16 * TPAD];
  const int blk = blockIdx.x;
  if (blk < 256) {
    mm2_fused_body(blk, emb, Wv + NE * NE, Wq, EQB, smem);
  } else if (blk < 512) {
    mm_body(blk - 256, emb, Wk, kp);
  } else if (blk < 512 + NB * NM) {
    gumbel_body(blk - 512, g);
  } else {
    prep_body(blk - 512 - NB * NM, emb, init_w, Whc, bhc, Wv, bv, Wq, qbase, q0W, smem);
  }
}

#define PIDX(h) (((h) >> 5) * 36 + ((h) & 31))

// ---------------- sequential decode: 1 block per batch item (R15-R18 proven form) ----------------
// Structural floor: 64 inherently sequential steps; per-step critical path =
// logit eval (VALU/trans issue) + dependent shfl reductions + cross-wave publish/combine
// + winner-row L2 fetch. Measured 278±2 µs across 5 structural variants (R15-R19).
__global__ __launch_bounds__(1024, 4) void decode_kernel(
    const float* __restrict__ emb,
    const float* __restrict__ node,
    const float* __restrict__ costs,
    const float* __restrict__ Wv,
    const float* __restrict__ Wq,
    const float* __restrict__ vptr,
    const float* __restrict__ g_g,
    const float* __restrict__ kp_g,
    const float* __restrict__ EQB_g,       // = exp(2*QB)
    const float* __restrict__ qbase_g,
    const float* __restrict__ q0W_g,
    float* __restrict__ out) {
  const int b = blockIdx.x;
  const int tid = threadIdx.x;
  const int hc = tid & 7;          // 32-float h-chunk
  const int pr = tid >> 3;         // s-pair 0..127
  const int s0 = pr * 2, s1 = s0 + 1;
  const int wid = tid >> 6;        // wave 0..15
  const int lane = tid & 63;

  __shared__ float qWp[8 * 36];    // e^{2q} (padded chunks)
  __shared__ float vpp[8 * 36];    // -2*vptr
  __shared__ float4 part4[16];     // per-wave argmax partial {val, idx, lg, -}
  __shared__ float2 mle[NM][17];   // per-step per-wave {max lg, sum exp(lg-ml)} (padded)
  __shared__ float blg_hist[NM];
  __shared__ int   idx_hist[NM];
  __shared__ float er[NE];
  __shared__ float Ts[NE];

  // ek = exp(2*kp) for 2 s x 32 h — READ-ONLY persistent block (64 VGPRs)
  float4 ek0[8], ek1[8];
  {
    const float4* p0 = (const float4*)(kp_g + ((size_t)b * NS + s0) * NH + hc * 32);
    const float4* p1 = (const float4*)(kp_g + ((size_t)b * NS + s1) * NH + hc * 32);
    #pragma unroll
    for (int j = 0; j < 8; ++j) {
      float4 a = p0[j], c = p1[j];
      ek0[j] = make_float4(__expf(2.f * a.x), __expf(2.f * a.y), __expf(2.f * a.z), __expf(2.f * a.w));
      ek1[j] = make_float4(__expf(2.f * c.x), __expf(2.f * c.y), __expf(2.f * c.z), __expf(2.f * c.w));
    }
  }
  float Vsum = 0.f;
  {
    const float4* vv = (const float4*)(vptr + hc * 32);
    #pragma unroll
    for (int j = 0; j < 8; ++j) { float4 v = vv[j]; Vsum += (v.x + v.y) + (v.z + v.w); }
  }
  if (tid < NH) {
    vpp[PIDX(tid)] = -2.0f * vptr[tid];
    qWp[PIDX(tid)] = __expf(2.0f * q0W_g[b * NH + tid]);   // step-0 e^{2q}
  }
  float e2qb = (tid < NH) ? __expf(2.0f * qbase_g[b * NH + tid]) : 0.f;

  int m = 0;
  const float* gb = g_g + (size_t)b * NM * NS;

  __syncthreads();

  for (int i = 0; i < NM; ++i) {
    // ---- phase A+B fused: per-pair logits + full per-wave reduce ----
    float lg0, lg1, val0, val1;
    if (!m) {
      float2 g01 = *(const float2*)(gb + i * NS + s0);     // same addr per 8-lane group
      const float4* q4 = (const float4*)(qWp + hc * 36);
      const float4* v4 = (const float4*)(vpp + hc * 36);
      float a0 = 0.f, a1 = 0.f;
      #pragma unroll
      for (int jj = 0; jj < 4; ++jj) {
        float4 qa = q4[2 * jj], qb = q4[2 * jj + 1];
        float4 va = v4[2 * jj], vb = v4[2 * jj + 1];
        {
          float4 ka = ek0[2 * jj], kb = ek0[2 * jj + 1];
          float z1 = fmaf(qa.x, ka.x, 1.f), z2 = fmaf(qa.y, ka.y, 1.f);
          float z3 = fmaf(qa.z, ka.z, 1.f), z4 = fmaf(qa.w, ka.w, 1.f);
          float z5 = fmaf(qb.x, kb.x, 1.f), z6 = fmaf(qb.y, kb.y, 1.f);
          float z7 = fmaf(qb.z, kb.z, 1.f), z8 = fmaf(qb.w, kb.w, 1.f);
          float p12 = z1 * z2, p34 = z3 * z4, p56 = z5 * z6, p78 = z7 * z8;
          float p1234 = p12 * p34, p5678 = p56 * p78;
          float r = __builtin_amdgcn_rcpf(p1234 * p5678);
          float t12 = fmaf(va.y, z1, va.x * z2);
          float t34 = fmaf(va.w, z3, va.z * z4);
          float t56 = fmaf(vb.y, z5, vb.x * z6);
          float t78 = fmaf(vb.w, z7, vb.z * z8);
          float T14 = fmaf(t34, p12, t12 * p34);
          float T58 = fmaf(t78, p56, t56 * p78);
          a0 = fmaf(T14 * p5678, r, a0);
          a0 = fmaf(T58 * p1234, r, a0);
        }
        {
          float4 ka = ek1[2 * jj], kb = ek1[2 * jj + 1];
          float z1 = fmaf(qa.x, ka.x, 1.f), z2 = fmaf(qa.y, ka.y, 1.f);
          float z3 = fmaf(qa.z, ka.z, 1.f), z4 = fmaf(qa.w, ka.w, 1.f);
          float z5 = fmaf(qb.x, kb.x, 1.f), z6 = fmaf(qb.y, kb.y, 1.f);
          float z7 = fmaf(qb.z, kb.z, 1.f), z8 = fmaf(qb.w, kb.w, 1.f);
          float p12 = z1 * z2, p34 = z3 * z4, p56 = z5 * z6, p78 = z7 * z8;
          float p1234 = p12 * p34, p5678 = p56 * p78;
          float r = __builtin_amdgcn_rcpf(p1234 * p5678);
          float t12 = fmaf(va.y, z1, va.x * z2);
          float t34 = fmaf(va.w, z3, va.z * z4);
          float t56 = fmaf(vb.y, z5, vb.x * z6);
          float t78 = fmaf(vb.w, z7, vb.z * z8);
          float T14 = fmaf(t34, p12, t12 * p34);
          float T58 = fmaf(t78, p56, t56 * p78);
          a1 = fmaf(T14 * p5678, r, a1);
          a1 = fmaf(T58 * p1234, r, a1);
        }
      }
      float u0 = Vsum + a0;
      float u1 = Vsum + a1;
      u0 += __shfl_xor(u0, 1); u0 += __shfl_xor(u0, 2); u0 += __shfl_xor(u0, 4);
      u1 += __shfl_xor(u1, 1); u1 += __shfl_xor(u1, 2); u1 += __shfl_xor(u1, 4);
      float ex0 = __expf(2.f * u0);
      float ex1 = __expf(2.f * u1);
      lg0 = fmaf(-20.f, __builtin_amdgcn_rcpf(ex0 + 1.f), 10.f);
      lg1 = fmaf(-20.f, __builtin_amdgcn_rcpf(ex1 + 1.f), 10.f);
      val0 = lg0 + g01.x;
      val1 = lg1 + g01.y;
    } else {
      lg0 = -1e9f; lg1 = -1e9f; val0 = -1e9f; val1 = -1e9f;
    }
    // wave-wide max(lg)
    float ml = fmaxf(lg0, lg1);
    #pragma unroll
    for (int off = 1; off < 64; off <<= 1) ml = fmaxf(ml, __shfl_xor(ml, off));
    // wave-wide sum exp(lg-ml): each pair replicated 8x -> scale by 1/8
    float e = (__expf(lg0 - ml) + __expf(lg1 - ml)) * 0.125f;
    #pragma unroll
    for (int off = 1; off < 64; off <<= 1) e += __shfl_xor(e, off);
    // wave-wide argmax carrying (val, idx, lg); first-index tiebreak
    bool t1 = val1 > val0;                  // tie -> s0 (smaller index)
    float v = t1 ? val1 : val0;
    int vi = t1 ? s1 : s0;
    float lgw = t1 ? lg1 : lg0;
    #pragma unroll
    for (int off = 1; off < 64; off <<= 1) {
      float ov = __shfl_xor(v, off);
      int   oi = __shfl_xor(vi, off);
      float ol = __shfl_xor(lgw, off);
      bool take = (ov > v) || (ov == v && oi < vi);
      v   = take ? ov : v;
      vi  = take ? oi : vi;
      lgw = take ? ol : lgw;
    }
    if (lane == 0) {
      part4[wid] = make_float4(v, __int_as_float(vi), lgw, 0.f);
      mle[i][wid] = make_float2(ml, e);
    }
    __syncthreads();                                    // sync1: partials ready

    // ---- phase C: 16-way combine on every lane ----
    float4 p = part4[lane & 15];
    float cv = p.x; int ci = __float_as_int(p.y); float cl = p.z;
    #pragma unroll
    for (int off = 1; off < 16; off <<= 1) {
      float ov = __shfl_xor(cv, off);
      int   oi = __shfl_xor(ci, off);
      float ol = __shfl_xor(cl, off);
      bool take = (ov > cv) || (ov == cv && oi < ci);
      cv = take ? ov : cv;
      ci = take ? oi : ci;
      cl = take ? ol : cl;
    }
    const int idx = ci;
    if (tid == 0) { idx_hist[i] = idx; blg_hist[i] = cl; }

    // mask whole 4-node cell of idx (thread covers half a cell)
    if (!m && (pr >> 1) == (idx >> 2)) m = 1;

    // one-time after step 0: fold exp(2*Qinit) into e2qb
    if (i == 0) {
      if (tid < NE) er[tid] = emb[((size_t)b * NS + idx) * NE + tid];
      __syncthreads();
      if (tid < NE) {
        float tv = 0.f;
        #pragma unroll 4
        for (int j = 0; j < NE; ++j) tv = fmaf(er[j], Wv[j * NE + tid], tv);
        Ts[tid] = tv;
      }
      __syncthreads();
      if (tid < NE) {
        float qi = 0.f;
        #pragma unroll 4
        for (int e2 = 0; e2 < NE; ++e2) qi = fmaf(Ts[e2], Wq[e2 * NH + tid], qi);
        e2qb *= __expf(2.0f * qi);
      }
    }

    // next step's e^{2q} = e2qb * EQB[idx] (1KB staging load -> LDS)
    if (tid < NH) qWp[PIDX(tid)] = e2qb * EQB_g[((size_t)b * NS + idx) * NH + tid];
    __syncthreads();                                    // sync2: qW ready
  }

  // ---- post-loop: wave 0 = logp (one step per lane), wave 1 = reward ----
  if (wid == 0) {
    float mlg = -3.0e38f;
    #pragma unroll 4
    for (int w = 0; w < 16; ++w) mlg = fmaxf(mlg, mle[lane][w].x);
    float sum = 0.f;
    #pragma unroll 4
    for (int w = 0; w < 16; ++w) {
      float2 me = mle[lane][w];
      sum += me.y * __expf(me.x - mlg);
    }
    float term = blg_hist[lane] - (mlg + logf(sum));
    #pragma unroll
    for (int off = 1; off < 64; off <<= 1) term += __shfl_xor(term, off);
    if (lane == 0) out[b] = term;
    out[2 * NB + b * NM + lane] = (float)idx_hist[lane];   // coalesced action write
  } else if (wid == 1) {
    float term = 0.f;
    if (lane > 0) {
      int id = idx_hist[lane];
      int pv = idx_hist[lane - 1];
      float dx = node[((size_t)b * NS + id) * 4 + 0] - node[((size_t)b * NS + pv) * 4 + 2];
      float dy = node[((size_t)b * NS + id) * 4 + 1] - node[((size_t)b * NS + pv) * 4 + 3];
      term = sqrtf(dx * dx + dy * dy) + costs[(size_t)b * NS + pv] + costs[(size_t)b * NS + id];
    }
    #pragma unroll
    for (int off = 1; off < 64; off <<= 1) term += __shfl_xor(term, off);
    if (lane == 0) out[NB + b] = term;
  }
}

extern "C" void kernel_launch(void* const* d_in, const int* in_sizes, int n_in,
                              void* d_out, int out_size, void* d_ws, size_t ws_size,
                              hipStream_t stream) {
  const float* emb    = (const float*)d_in[0];
  const float* node   = (const float*)d_in[1];
  const float* costs  = (const float*)d_in[4];
  const float* init_w = (const float*)d_in[5];
  const float* Whc    = (const float*)d_in[6];
  const float* bhc    = (const float*)d_in[7];
  const float* Wv     = (const float*)d_in[8];
  const float* bv     = (const float*)d_in[9];
  const float* Wq     = (const float*)d_in[10];
  const float* Wk     = (const float*)d_in[11];
  const float* vptr   = (const float*)d_in[12];
  float* out = (float*)d_out;

  float* ws    = (float*)d_ws;
  float* g     = ws;
  float* kp    = g + NB * NM * NS;
  float* QB    = kp + (size_t)NB * NS * NH;
  float* spare = QB + (size_t)NB * NS * NH;    // unused (layout stability)
  float* qbase = spare + (size_t)NB * NS * NE;
  float* q0W   = qbase + NB * NH;

  // ONE pre-kernel: EQB-chained (0-255) | mm1->kp (256-511) | gumbel (512-1535) | prep (1536-1551)
  fused_pre_kernel<<<512 + NB * NM + NB, 256, 0, stream>>>(
      g, emb, init_w, Whc, bhc, Wv, bv, Wq, Wk, qbase, q0W, kp, QB);
  // decode (R15-R18 proven form)
  decode_kernel<<<NB, 1024, 0, stream>>>(emb, node, costs, Wv, Wq, vptr,
                                         g, kp, QB, qbase, q0W, out);
}